// Round 15
// baseline (208.935 us; speedup 1.0000x reference)
//
#include <hip/hip_runtime.h>
#include <hip/hip_bf16.h>

#define NN 768
#define MD 1024
#define NPAIR 295296            // 768*769/2
#define NBLK4 4614              // NPAIR / 64 (exact)

typedef __attribute__((ext_vector_type(8))) short s16x8;
typedef __attribute__((ext_vector_type(4))) float f32x4;
typedef __attribute__((ext_vector_type(2))) float f32x2;
typedef __attribute__((ext_vector_type(2))) __bf16 b16x2;

__device__ __forceinline__ ushort bf16_rn(float f) {
    uint u = __builtin_bit_cast(uint, f);
    u += 0x7FFFu + ((u >> 16) & 1u);
    return (ushort)(u >> 16);
}

// inverse triangular index: p -> (i,j), off(i) = i*(1537-i)/2, j = i + p - off(i)
__device__ __forceinline__ void ptoij(int p, int& io, int& jo) {
    const float disc = (float)(1537 * 1537 - 8 * p);
    int i = (int)((1537.0f - sqrtf(disc)) * 0.5f);
    i = i < 0 ? 0 : (i > 767 ? 767 : i);
    while (i > 0 && p < i * (1537 - i) / 2) --i;
    while (i < 767 && p >= (i + 1) * (1536 - i) / 2) ++i;
    io = i;
    jo = i + (p - i * (1537 - i) / 2);
}

#define GLOAD16(gsrc, ldst)                                                        \
    __builtin_amdgcn_global_load_lds(                                              \
        (const __attribute__((address_space(1))) void*)(gsrc),                     \
        (__attribute__((address_space(3))) void*)(ldst), 16, 0, 0)

// ---------- one-time: W2 -> bf16 (RNE), chunk-major + XOR-swizzled -------------
// chunk c (m0=c*64): 128 rows(k) x 128B; byte-in-row = (mg*16) ^ ((k&7)<<4)
__global__ __launch_bounds__(256) void w2bf16(const float* __restrict__ W2,
                                              ushort* __restrict__ WhiS)
{
    const int id = blockIdx.x * 256 + threadIdx.x;
    const int k = id >> 7;
    const int m = (id & 127) * 8;
    const float4 a = *reinterpret_cast<const float4*>(W2 + k * MD + m);
    const float4 b = *reinterpret_cast<const float4*>(W2 + k * MD + m + 4);
    const float w[8] = {a.x, a.y, a.z, a.w, b.x, b.y, b.z, b.w};
    s16x8 h;
#pragma unroll
    for (int e = 0; e < 8; ++e) h[e] = (short)bf16_rn(w[e]);
    const int c = m >> 6;
    const int mg = (m >> 3) & 7;
    const int byte = (mg * 16) ^ ((k & 7) << 4);
    const int off = c * 8192 + ((k * 128 + byte) >> 1);
    *reinterpret_cast<s16x8*>(&WhiS[off]) = h;
}

// ---------- one-time: pre-scaled layer-1 params (global, L1/L2-hot) ------------
__global__ __launch_bounds__(256) void prep1(const float* __restrict__ W1,
                                             const float* __restrict__ b1,
                                             float* __restrict__ SA,
                                             float* __restrict__ SC,
                                             float* __restrict__ SB)
{
    const int m = blockIdx.x * 256 + threadIdx.x;    // grid 4
    const float NL2E = -1.4426950408889634f;
    const float2 w = reinterpret_cast<const float2*>(W1)[m];
    SA[m] = w.x * NL2E;
    SC[m] = w.y * NL2E;
    SB[m] = b1[m] * NL2E;
}

// ---- macros (ambient locals) ---------------------------------------------------
#define STAGE(cc, buf)                                                       \
    {                                                                        \
        const ushort* sh_ = WhiS + (cc) * 8192;                              \
        _Pragma("unroll")                                                    \
        for (int q_ = 0; q_ < 4; ++q_) {                                     \
            const int off_ = (wv * 4 + q_) * 512;                            \
            GLOAD16(sh_ + off_ + lane * 8, &Wh[buf][off_]);                  \
        }                                                                    \
    }

// params pre-scaled by -log2(e): sigma = rcp(1 + 2^u); 8 values -> ah[ks]
#define SIG_CHUNK(cc)                                                        \
    {                                                                        \
        _Pragma("unroll")                                                    \
        for (int ks_ = 0; ks_ < 2; ++ks_) {                                  \
            const int m0_ = (cc) * 64 + ks_ * 32 + l4 * 8;                   \
            const f32x4 a0_ = *reinterpret_cast<const f32x4*>(SA + m0_);     \
            const f32x4 a1_ = *reinterpret_cast<const f32x4*>(SA + m0_ + 4); \
            const f32x4 c0_ = *reinterpret_cast<const f32x4*>(SC + m0_);     \
            const f32x4 c1_ = *reinterpret_cast<const f32x4*>(SC + m0_ + 4); \
            const f32x4 b0_ = *reinterpret_cast<const f32x4*>(SB + m0_);     \
            const f32x4 b1_ = *reinterpret_cast<const f32x4*>(SB + m0_ + 4); \
            const f32x2 xi2_ = (f32x2){xi, xi};                              \
            const f32x2 xj2_ = (f32x2){xj, xj};                              \
            const f32x2 one2_ = (f32x2){1.f, 1.f};                           \
            union { s16x8 v; uint u[4]; } fr_;                               \
            _Pragma("unroll")                                                \
            for (int h_ = 0; h_ < 4; ++h_) {                                 \
                f32x2 av_, cv_, bv_;                                         \
                if (h_ < 2) {                                                \
                    av_ = (f32x2){a0_[2 * h_], a0_[2 * h_ + 1]};             \
                    cv_ = (f32x2){c0_[2 * h_], c0_[2 * h_ + 1]};             \
                    bv_ = (f32x2){b0_[2 * h_], b0_[2 * h_ + 1]};             \
                } else {                                                     \
                    av_ = (f32x2){a1_[2 * h_ - 4], a1_[2 * h_ - 3]};         \
                    cv_ = (f32x2){c1_[2 * h_ - 4], c1_[2 * h_ - 3]};         \
                    bv_ = (f32x2){b1_[2 * h_ - 4], b1_[2 * h_ - 3]};         \
                }                                                            \
                const f32x2 u2_ = __builtin_elementwise_fma(                 \
                    xi2_, av_, __builtin_elementwise_fma(xj2_, cv_, bv_));   \
                f32x2 e2_;                                                   \
                e2_[0] = __builtin_amdgcn_exp2f(u2_[0]);                     \
                e2_[1] = __builtin_amdgcn_exp2f(u2_[1]);                     \
                const f32x2 t2_ = e2_ + one2_;                               \
                b16x2 p_;                                                    \
                p_.x = (__bf16)__builtin_amdgcn_rcpf(t2_[0]);                \
                p_.y = (__bf16)__builtin_amdgcn_rcpf(t2_[1]);                \
                fr_.u[h_] = __builtin_bit_cast(uint, p_);                    \
            }                                                                \
            ah[ks_] = fr_.v;                                                 \
        }                                                                    \
    }

#define MFMA_STEP(buf)                                                       \
    {                                                                        \
        _Pragma("unroll")                                                    \
        for (int ks_ = 0; ks_ < 2; ++ks_) {                                  \
            s16x8 bh_[8];                                                    \
            _Pragma("unroll")                                                \
            for (int tn_ = 0; tn_ < 8; ++tn_) {                              \
                const int k_ = tn_ * 16 + l15;                               \
                const int byte_ = (ks_ * 64 + l4 * 16) ^ ((k_ & 7) << 4);    \
                const int idx_ = (k_ * 128 + byte_) >> 1;                    \
                bh_[tn_] = *reinterpret_cast<const s16x8*>(&Wh[buf][idx_]);  \
            }                                                                \
            __builtin_amdgcn_s_setprio(1);                                   \
            _Pragma("unroll")                                                \
            for (int tn_ = 0; tn_ < 8; ++tn_)                                \
                acc[tn_] = __builtin_amdgcn_mfma_f32_16x16x32_bf16(          \
                    ah[ks_], bh_[tn_], acc[tn_], 0, 0, 0);                   \
            __builtin_amdgcn_s_setprio(0);                                   \
        }                                                                    \
    }

// ---------- main: 16 pairs/wave, 4 waves/block, 4 blocks/CU (4 waves/SIMD) -----
__global__ __launch_bounds__(256, 4) void mlp4(
    const float* __restrict__ x,
    const float* __restrict__ SA, const float* __restrict__ SC,
    const float* __restrict__ SB,
    const ushort* __restrict__ WhiS,
    const float* __restrict__ b2, const float* __restrict__ W3,
    const float* __restrict__ b3, float* __restrict__ K)
{
    __shared__ __align__(16) ushort Wh[2][8192];     // 32 KB only

    const int t = threadIdx.x;
    const int lane = t & 63, wv = t >> 6;
    const int l15 = lane & 15, l4 = lane >> 4;

    const int pairbase = blockIdx.x * 64 + wv * 16;  // NPAIR = 4614*64 exact

    int pi, pj;
    ptoij(pairbase + l15, pi, pj);
    const float xi = x[pi];
    const float xj = x[pj];

    f32x4 acc[8];
#pragma unroll
    for (int b = 0; b < 8; ++b) acc[b] = (f32x4){0.f, 0.f, 0.f, 0.f};

    STAGE(0, 0);
    __syncthreads();                 // Wh[0] staged (barrier drains vmcnt)

    s16x8 ah[2];
    for (int c = 0; c < 16; ++c) {
        if (c < 15) STAGE(c + 1, (c + 1) & 1);   // async into other buffer
        SIG_CHUNK(c);                            // VALU while loads fly
        MFMA_STEP(c & 1);
        __syncthreads();             // next buf ready; all reads of cur buf done
    }

    // epilogue: v = sum_k W3[k]*relu(h2 + b2[k]) + b3; reduce over 16 lanes (k)
    float w3v[8], b2v[8];
#pragma unroll
    for (int tn = 0; tn < 8; ++tn) {
        const int k = tn * 16 + l15;
        w3v[tn] = W3[k];
        b2v[tn] = b2[k];
    }
    const float b3v = b3[0];
#pragma unroll
    for (int r = 0; r < 4; ++r) {
        float v = 0.f;
#pragma unroll
        for (int tn = 0; tn < 8; ++tn)
            v = fmaf(w3v[tn], fmaxf(acc[tn][r] + b2v[tn], 0.f), v);
        v += __shfl_xor(v, 1, 16);
        v += __shfl_xor(v, 2, 16);
        v += __shfl_xor(v, 4, 16);
        v += __shfl_xor(v, 8, 16);
        if (l15 == 0) {
            int i, j;
            ptoij(pairbase + l4 * 4 + r, i, j);
            K[i * NN + j] = v + b3v;
        }
    }
}

// ---------- fallback fp32 MLP kernel (only if ws too small; never expected) ----
#define MC 32
#define JT 128
#define SPAD 132
__global__ __launch_bounds__(256) void mlp_fill(
    const float* __restrict__ x,
    const float* __restrict__ W1, const float* __restrict__ b1,
    const float* __restrict__ W2, const float* __restrict__ b2,
    const float* __restrict__ W3, const float* __restrict__ b3,
    float* __restrict__ K)
{
    const int i  = blockIdx.y;
    const int j0 = blockIdx.x * JT;
    if (j0 + JT - 1 < i) return;
    __shared__ float sA[MD];
    __shared__ float sCw[MD];
    __shared__ float sxj[JT];
    __shared__ float S[MC][SPAD];
    __shared__ float W2t[MC][SPAD];
    const int t = threadIdx.x;
    const float xi = x[i];
    for (int m = t; m < MD; m += 256) {
        const float2 w = reinterpret_cast<const float2*>(W1)[m];
        sA[m]  = fmaf(xi, w.x, b1[m]);
        sCw[m] = w.y;
    }
    if (t < JT) sxj[t] = x[j0 + t];
    const int tk = t & 15;
    const int tj = t >> 4;
    float w3r[8], b2r[8];
#pragma unroll
    for (int kk = 0; kk < 8; kk++) {
        w3r[kk] = W3[tk * 8 + kk];
        b2r[kk] = b2[tk * 8 + kk];
    }
    float acc[8][8];
#pragma unroll
    for (int jj = 0; jj < 8; jj++)
#pragma unroll
        for (int kk = 0; kk < 8; kk++) acc[jj][kk] = 0.f;
    const int jx   = t & 127;
    const int mseg = (t >> 7) * 16;
    __syncthreads();
    const float xjv = sxj[jx];
    for (int m0 = 0; m0 < MD; m0 += MC) {
#pragma unroll
        for (int q = 0; q < 4; q++) {
            const int f   = t + q * 256;
            const int k   = f >> 3;
            const int mm4 = (f & 7) * 4;
            const float4 w = *reinterpret_cast<const float4*>(W2 + k * MD + m0 + mm4);
            W2t[mm4 + 0][k] = w.x;
            W2t[mm4 + 1][k] = w.y;
            W2t[mm4 + 2][k] = w.z;
            W2t[mm4 + 3][k] = w.w;
        }
#pragma unroll
        for (int q = 0; q < 16; q++) {
            const int ml = mseg + q;
            const float z = fmaf(xjv, sCw[m0 + ml], sA[m0 + ml]);
            S[ml][jx] = 1.0f / (1.0f + __expf(-z));
        }
        __syncthreads();
#pragma unroll 4
        for (int mm = 0; mm < MC; mm++) {
            const float4 s0 = *reinterpret_cast<const float4*>(&S[mm][tj * 8]);
            const float4 s1 = *reinterpret_cast<const float4*>(&S[mm][tj * 8 + 4]);
            const float4 w0 = *reinterpret_cast<const float4*>(&W2t[mm][tk * 8]);
            const float4 w1 = *reinterpret_cast<const float4*>(&W2t[mm][tk * 8 + 4]);
            const float sj[8] = {s0.x, s0.y, s0.z, s0.w, s1.x, s1.y, s1.z, s1.w};
            const float wk[8] = {w0.x, w0.y, w0.z, w0.w, w1.x, w1.y, w1.z, w1.w};
#pragma unroll
            for (int jj = 0; jj < 8; jj++)
#pragma unroll
                for (int kk = 0; kk < 8; kk++)
                    acc[jj][kk] = fmaf(sj[jj], wk[kk], acc[jj][kk]);
        }
        __syncthreads();
    }
    const float b3v = b3[0];
#pragma unroll
    for (int jj = 0; jj < 8; jj++) {
        float v = 0.f;
#pragma unroll
        for (int kk = 0; kk < 8; kk++) {
            const float h = acc[jj][kk] + b2r[kk];
            v = fmaf(w3r[kk], fmaxf(h, 0.f), v);
        }
#pragma unroll
        for (int off = 8; off >= 1; off >>= 1)
            v += __shfl_xor(v, off, 16);
        if (tk == 0) {
            const int j = j0 + tj * 8 + jj;
            if (j >= i) K[i * NN + j] = v + b3v;
        }
    }
}

// ---------- Kernel 2: C = K^T K, symmetric — compute upper tiles, mirror -------
__global__ __launch_bounds__(256) void ktk(const float* __restrict__ K,
                                           float* __restrict__ C)
{
    const int b0 = blockIdx.x * 64;
    const int a0 = blockIdx.y * 64;
    if (b0 < a0) return;             // C symmetric: only tiles with b0 >= a0
    __shared__ float Ka[64][68];
    __shared__ float Kb[64][68];
    const int t  = threadIdx.x;
    const int tb = t & 15;
    const int ta = t >> 4;
    float acc[4][4];
#pragma unroll
    for (int u = 0; u < 4; u++)
#pragma unroll
        for (int v = 0; v < 4; v++) acc[u][v] = 0.f;
    const int kmax = a0 + 64;        // K[k][a]=0 for k>a; a0 <= b0
    for (int k0 = 0; k0 < kmax; k0 += 64) {
#pragma unroll
        for (int q = 0; q < 4; q++) {
            const int f  = t + q * 256;
            const int kk = f >> 4;
            const int c4 = (f & 15) * 4;
            *reinterpret_cast<float4*>(&Ka[kk][c4]) =
                *reinterpret_cast<const float4*>(K + (k0 + kk) * NN + a0 + c4);
            *reinterpret_cast<float4*>(&Kb[kk][c4]) =
                *reinterpret_cast<const float4*>(K + (k0 + kk) * NN + b0 + c4);
        }
        __syncthreads();
#pragma unroll 8
        for (int kk = 0; kk < 64; kk++) {
            const float4 av = *reinterpret_cast<const float4*>(&Ka[kk][ta * 4]);
            const float4 bv = *reinterpret_cast<const float4*>(&Kb[kk][tb * 4]);
            const float a4[4] = {av.x, av.y, av.z, av.w};
            const float b4[4] = {bv.x, bv.y, bv.z, bv.w};
#pragma unroll
            for (int u = 0; u < 4; u++)
#pragma unroll
                for (int v = 0; v < 4; v++)
                    acc[u][v] = fmaf(a4[u], b4[v], acc[u][v]);
        }
        __syncthreads();
    }
#pragma unroll
    for (int u = 0; u < 4; u++) {
        float4 o;
        o.x = acc[u][0]; o.y = acc[u][1]; o.z = acc[u][2]; o.w = acc[u][3];
        *reinterpret_cast<float4*>(C + (a0 + ta * 4 + u) * NN + b0 + tb * 4) = o;
    }
    if (b0 > a0) {                   // mirror tile: C[b][a] = C[a][b], coalesced
#pragma unroll
        for (int v = 0; v < 4; v++) {
            float4 o;
            o.x = acc[0][v]; o.y = acc[1][v]; o.z = acc[2][v]; o.w = acc[3][v];
            *reinterpret_cast<float4*>(C + (b0 + tb * 4 + v) * NN + a0 + ta * 4) = o;
        }
    }
}

extern "C" void kernel_launch(void* const* d_in, const int* in_sizes, int n_in,
                              void* d_out, int out_size, void* d_ws, size_t ws_size,
                              hipStream_t stream)
{
    const float* x  = (const float*)d_in[0];
    const float* W1 = (const float*)d_in[1];
    const float* b1 = (const float*)d_in[2];
    const float* W2 = (const float*)d_in[3];
    const float* b2 = (const float*)d_in[4];
    const float* W3 = (const float*)d_in[5];
    const float* b3 = (const float*)d_in[6];
    float* Kmat = (float*)d_ws;                       // 2,359,296 B
    float* C    = (float*)d_out;

    const size_t kBytes = (size_t)NN * NN * sizeof(float);
    const size_t wBytes = 262144;                     // W2 bf16 swizzled
    const size_t pBytes = 3 * MD * sizeof(float);     // SA/SC/SB = 12 KB
    const size_t need   = kBytes + wBytes + pBytes;

    hipMemsetAsync(Kmat, 0, kBytes, stream);
    if (ws_size >= need) {
        ushort* WhiS = (ushort*)((char*)d_ws + kBytes);
        float*  SA   = (float*)((char*)d_ws + kBytes + wBytes);
        float*  SC   = SA + MD;
        float*  SB   = SC + MD;
        w2bf16<<<64, 256, 0, stream>>>(W2, WhiS);
        prep1<<<4, 256, 0, stream>>>(W1, b1, SA, SC, SB);
        mlp4<<<NBLK4, 256, 0, stream>>>(x, SA, SC, SB, WhiS, b2, W3, b3, Kmat);
    } else {
        mlp_fill<<<dim3(6, NN), 256, 0, stream>>>(x, W1, b1, W2, b2, W3, b3, Kmat);
    }
    ktk<<<dim3(NN / 64, NN / 64), 256, 0, stream>>>(Kmat, C);
}

// Round 16
// 166.086 us; speedup vs baseline: 1.2580x; 1.2580x over previous
//
#include <hip/hip_runtime.h>
#include <hip/hip_bf16.h>

#define NN 768
#define MD 1024
#define NPAIR 295296            // 768*769/2
#define NPBLK2 2307             // NPAIR / 128 (exact)

typedef __attribute__((ext_vector_type(8))) short s16x8;
typedef __attribute__((ext_vector_type(4))) float f32x4;
typedef __attribute__((ext_vector_type(2))) float f32x2;
typedef __attribute__((ext_vector_type(2))) __bf16 b16x2;

__device__ __forceinline__ ushort bf16_rn(float f) {
    uint u = __builtin_bit_cast(uint, f);
    u += 0x7FFFu + ((u >> 16) & 1u);
    return (ushort)(u >> 16);
}

// inverse triangular index: p -> (i,j), off(i) = i*(1537-i)/2, j = i + p - off(i)
__device__ __forceinline__ void ptoij(int p, int& io, int& jo) {
    const float disc = (float)(1537 * 1537 - 8 * p);
    int i = (int)((1537.0f - sqrtf(disc)) * 0.5f);
    i = i < 0 ? 0 : (i > 767 ? 767 : i);
    while (i > 0 && p < i * (1537 - i) / 2) --i;
    while (i < 767 && p >= (i + 1) * (1536 - i) / 2) ++i;
    io = i;
    jo = i + (p - i * (1537 - i) / 2);
}

// ---------- one-time: W2 -> bf16, FRAGMENT-major for register-direct loads -----
// frag f = ((c*2+ks)*8 + tn); WF[f*512 + lane*8 + e] = W2bf16[k][m]
// with k = tn*16 + (lane&15), m = c*64 + ks*32 + (lane>>4)*8 + e
__global__ __launch_bounds__(256) void w2frag(const float* __restrict__ W2,
                                              ushort* __restrict__ WF)
{
    const int id = blockIdx.x * 256 + threadIdx.x;   // 0..16383
    const int lane = id & 63;
    const int f = id >> 6;          // 0..255
    const int tn = f & 7;
    const int ks = (f >> 3) & 1;
    const int c  = f >> 4;
    const int k = tn * 16 + (lane & 15);
    const int m = c * 64 + ks * 32 + (lane >> 4) * 8;
    const float4 a = *reinterpret_cast<const float4*>(W2 + k * MD + m);
    const float4 b = *reinterpret_cast<const float4*>(W2 + k * MD + m + 4);
    const float w[8] = {a.x, a.y, a.z, a.w, b.x, b.y, b.z, b.w};
    s16x8 h;
#pragma unroll
    for (int e = 0; e < 8; ++e) h[e] = (short)bf16_rn(w[e]);
    *reinterpret_cast<s16x8*>(WF + id * 8) = h;
}

// ---- macros (ambient locals) ---------------------------------------------------
// load one ks-half of a chunk's B-fragments into registers (8 coalesced 1KB loads)
#define LOADB(cc, ks)                                                        \
    {                                                                        \
        const ushort* wb_ = WF + (cc) * 8192 + (ks) * 4096 + lane * 8;       \
        _Pragma("unroll")                                                    \
        for (int tn_ = 0; tn_ < 8; ++tn_)                                    \
            bh[tn_] = *reinterpret_cast<const s16x8*>(wb_ + tn_ * 512);      \
    }

// weights in sa/sc/sb pre-scaled by -log2(e): sigma = rcp(1 + 2^u)
// one ks-half (32 m): its ~320cy of VALU covers the in-flight bh loads
#define SIG_HALF(cc, ks_)                                                    \
    {                                                                        \
        const int m0_ = (cc) * 64 + (ks_) * 32 + l4 * 8;                     \
        const f32x4 a0_ = *reinterpret_cast<const f32x4*>(&sa[m0_]);         \
        const f32x4 a1_ = *reinterpret_cast<const f32x4*>(&sa[m0_ + 4]);     \
        const f32x4 c0_ = *reinterpret_cast<const f32x4*>(&sc[m0_]);         \
        const f32x4 c1_ = *reinterpret_cast<const f32x4*>(&sc[m0_ + 4]);     \
        const f32x4 b0_ = *reinterpret_cast<const f32x4*>(&sb[m0_]);         \
        const f32x4 b1_ = *reinterpret_cast<const f32x4*>(&sb[m0_ + 4]);     \
        _Pragma("unroll")                                                    \
        for (int tm_ = 0; tm_ < 2; ++tm_) {                                  \
            const f32x2 xi2_ = (f32x2){xia[tm_], xia[tm_]};                  \
            const f32x2 xj2_ = (f32x2){xja[tm_], xja[tm_]};                  \
            const f32x2 one2_ = (f32x2){1.f, 1.f};                           \
            union { s16x8 v; uint u[4]; } fr_;                               \
            _Pragma("unroll")                                                \
            for (int h_ = 0; h_ < 4; ++h_) {                                 \
                f32x2 av_, cv_, bv_;                                         \
                if (h_ < 2) {                                                \
                    av_ = (f32x2){a0_[2 * h_], a0_[2 * h_ + 1]};             \
                    cv_ = (f32x2){c0_[2 * h_], c0_[2 * h_ + 1]};             \
                    bv_ = (f32x2){b0_[2 * h_], b0_[2 * h_ + 1]};             \
                } else {                                                     \
                    av_ = (f32x2){a1_[2 * h_ - 4], a1_[2 * h_ - 3]};         \
                    cv_ = (f32x2){c1_[2 * h_ - 4], c1_[2 * h_ - 3]};         \
                    bv_ = (f32x2){b1_[2 * h_ - 4], b1_[2 * h_ - 3]};         \
                }                                                            \
                const f32x2 u2_ = __builtin_elementwise_fma(                 \
                    xi2_, av_, __builtin_elementwise_fma(xj2_, cv_, bv_));   \
                f32x2 e2_;                                                   \
                e2_[0] = __builtin_amdgcn_exp2f(u2_[0]);                     \
                e2_[1] = __builtin_amdgcn_exp2f(u2_[1]);                     \
                const f32x2 t2_ = e2_ + one2_;                               \
                b16x2 p_;                                                    \
                p_.x = (__bf16)__builtin_amdgcn_rcpf(t2_[0]);                \
                p_.y = (__bf16)__builtin_amdgcn_rcpf(t2_[1]);                \
                fr_.u[h_] = __builtin_bit_cast(uint, p_);                    \
            }                                                                \
            ah[tm_] = fr_.v;                                                 \
        }                                                                    \
    }

#define MFMA_HALF()                                                          \
    {                                                                        \
        __builtin_amdgcn_s_setprio(1);                                       \
        _Pragma("unroll")                                                    \
        for (int tm_ = 0; tm_ < 2; ++tm_)                                    \
            _Pragma("unroll")                                                \
            for (int tn_ = 0; tn_ < 8; ++tn_)                                \
                acc[tm_][tn_] = __builtin_amdgcn_mfma_f32_16x16x32_bf16(     \
                    ah[tm_], bh[tn_], acc[tm_][tn_], 0, 0, 0);               \
        __builtin_amdgcn_s_setprio(0);                                       \
    }

// ---------- main: 32 pairs/wave, B-frags in registers, ZERO loop barriers ------
// per chunk: SIGk0 (covers ks0 loads) -> MFMA0 -> issue ks1 loads ->
//            SIGk1 (covers ks1 loads) -> MFMA1 -> issue next ks0 loads
__global__ __launch_bounds__(256, 3) void mlp_pairs_reg(
    const float* __restrict__ x,
    const float* __restrict__ W1, const float* __restrict__ b1,
    const ushort* __restrict__ WF,
    const float* __restrict__ b2, const float* __restrict__ W3,
    const float* __restrict__ b3, float* __restrict__ K)
{
    __shared__ __align__(16) float sa[MD], sc[MD], sb[MD];   // 12 KB total

    const int t = threadIdx.x;
    const int lane = t & 63;
    const int l15 = lane & 15, l4 = lane >> 4;
    const int wv = t >> 6;

    const float NL2E = -1.4426950408889634f;
    for (int m = t; m < MD; m += 256) {
        const float2 w = reinterpret_cast<const float2*>(W1)[m];
        sa[m] = w.x * NL2E;
        sc[m] = w.y * NL2E;
        sb[m] = b1[m] * NL2E;
    }

    const int pairbase = blockIdx.x * 128 + wv * 32;

    float xia[2], xja[2];
#pragma unroll
    for (int tm = 0; tm < 2; ++tm) {
        const int p = pairbase + tm * 16 + l15;
        if (p < NPAIR) {
            int i, j;
            ptoij(p, i, j);
            xia[tm] = x[i];
            xja[tm] = x[j];
        } else {
            xia[tm] = 0.f;
            xja[tm] = 0.f;
        }
    }

    f32x4 acc[2][8];
#pragma unroll
    for (int a = 0; a < 2; ++a)
#pragma unroll
        for (int b = 0; b < 8; ++b) acc[a][b] = (f32x4){0.f, 0.f, 0.f, 0.f};

    s16x8 bh[8];
    LOADB(0, 0);                     // issue chunk0/ks0 frag loads (global->reg)
    __syncthreads();                 // sa/sc/sb ready (the ONLY block barrier)

    s16x8 ah[2];
    for (int c = 0; c < 16; ++c) {
        SIG_HALF(c, 0);              // VALU covers in-flight ks0 loads
        MFMA_HALF();                 // consumes bh=ks0
        LOADB(c, 1);                 // refill bh with ks1 frags
        SIG_HALF(c, 1);              // VALU covers ks1 loads
        MFMA_HALF();                 // consumes bh=ks1
        if (c < 15) LOADB(c + 1, 0); // next chunk ks0 flies under next SIG
    }

    // epilogue: v = sum_k W3[k]*relu(h2 + b2[k]) + b3; reduce over 16 lanes (k)
    float w3v[8], b2v[8];
#pragma unroll
    for (int tn = 0; tn < 8; ++tn) {
        const int k = tn * 16 + l15;
        w3v[tn] = W3[k];
        b2v[tn] = b2[k];
    }
    const float b3v = b3[0];
#pragma unroll
    for (int tm = 0; tm < 2; ++tm)
#pragma unroll
        for (int r = 0; r < 4; ++r) {
            float v = 0.f;
#pragma unroll
            for (int tn = 0; tn < 8; ++tn)
                v = fmaf(w3v[tn], fmaxf(acc[tm][tn][r] + b2v[tn], 0.f), v);
            v += __shfl_xor(v, 1, 16);
            v += __shfl_xor(v, 2, 16);
            v += __shfl_xor(v, 4, 16);
            v += __shfl_xor(v, 8, 16);
            if (l15 == 0) {
                const int p = pairbase + tm * 16 + l4 * 4 + r;
                if (p < NPAIR) {
                    int i, j;
                    ptoij(p, i, j);
                    K[i * NN + j] = v + b3v;
                }
            }
        }
}

// ---------- fallback fp32 MLP kernel (only if ws too small; never expected) ----
#define MC 32
#define JT 128
#define SPAD 132
__global__ __launch_bounds__(256) void mlp_fill(
    const float* __restrict__ x,
    const float* __restrict__ W1, const float* __restrict__ b1,
    const float* __restrict__ W2, const float* __restrict__ b2,
    const float* __restrict__ W3, const float* __restrict__ b3,
    float* __restrict__ K)
{
    const int i  = blockIdx.y;
    const int j0 = blockIdx.x * JT;
    if (j0 + JT - 1 < i) return;
    __shared__ float sA[MD];
    __shared__ float sCw[MD];
    __shared__ float sxj[JT];
    __shared__ float S[MC][SPAD];
    __shared__ float W2t[MC][SPAD];
    const int t = threadIdx.x;
    const float xi = x[i];
    for (int m = t; m < MD; m += 256) {
        const float2 w = reinterpret_cast<const float2*>(W1)[m];
        sA[m]  = fmaf(xi, w.x, b1[m]);
        sCw[m] = w.y;
    }
    if (t < JT) sxj[t] = x[j0 + t];
    const int tk = t & 15;
    const int tj = t >> 4;
    float w3r[8], b2r[8];
#pragma unroll
    for (int kk = 0; kk < 8; kk++) {
        w3r[kk] = W3[tk * 8 + kk];
        b2r[kk] = b2[tk * 8 + kk];
    }
    float acc[8][8];
#pragma unroll
    for (int jj = 0; jj < 8; jj++)
#pragma unroll
        for (int kk = 0; kk < 8; kk++) acc[jj][kk] = 0.f;
    const int jx   = t & 127;
    const int mseg = (t >> 7) * 16;
    __syncthreads();
    const float xjv = sxj[jx];
    for (int m0 = 0; m0 < MD; m0 += MC) {
#pragma unroll
        for (int q = 0; q < 4; q++) {
            const int f   = t + q * 256;
            const int k   = f >> 3;
            const int mm4 = (f & 7) * 4;
            const float4 w = *reinterpret_cast<const float4*>(W2 + k * MD + m0 + mm4);
            W2t[mm4 + 0][k] = w.x;
            W2t[mm4 + 1][k] = w.y;
            W2t[mm4 + 2][k] = w.z;
            W2t[mm4 + 3][k] = w.w;
        }
#pragma unroll
        for (int q = 0; q < 16; q++) {
            const int ml = mseg + q;
            const float z = fmaf(xjv, sCw[m0 + ml], sA[m0 + ml]);
            S[ml][jx] = 1.0f / (1.0f + __expf(-z));
        }
        __syncthreads();
#pragma unroll 4
        for (int mm = 0; mm < MC; mm++) {
            const float4 s0 = *reinterpret_cast<const float4*>(&S[mm][tj * 8]);
            const float4 s1 = *reinterpret_cast<const float4*>(&S[mm][tj * 8 + 4]);
            const float4 w0 = *reinterpret_cast<const float4*>(&W2t[mm][tk * 8]);
            const float4 w1 = *reinterpret_cast<const float4*>(&W2t[mm][tk * 8 + 4]);
            const float sj[8] = {s0.x, s0.y, s0.z, s0.w, s1.x, s1.y, s1.z, s1.w};
            const float wk[8] = {w0.x, w0.y, w0.z, w0.w, w1.x, w1.y, w1.z, w1.w};
#pragma unroll
            for (int jj = 0; jj < 8; jj++)
#pragma unroll
                for (int kk = 0; kk < 8; kk++)
                    acc[jj][kk] = fmaf(sj[jj], wk[kk], acc[jj][kk]);
        }
        __syncthreads();
    }
    const float b3v = b3[0];
#pragma unroll
    for (int jj = 0; jj < 8; jj++) {
        float v = 0.f;
#pragma unroll
        for (int kk = 0; kk < 8; kk++) {
            const float h = acc[jj][kk] + b2r[kk];
            v = fmaf(w3r[kk], fmaxf(h, 0.f), v);
        }
#pragma unroll
        for (int off = 8; off >= 1; off >>= 1)
            v += __shfl_xor(v, off, 16);
        if (tk == 0) {
            const int j = j0 + tj * 8 + jj;
            if (j >= i) K[i * NN + j] = v + b3v;
        }
    }
}

// ---------- Kernel 2: C = K^T K, symmetric — compute upper tiles, mirror -------
__global__ __launch_bounds__(256) void ktk(const float* __restrict__ K,
                                           float* __restrict__ C)
{
    const int b0 = blockIdx.x * 64;
    const int a0 = blockIdx.y * 64;
    if (b0 < a0) return;             // C symmetric: only tiles with b0 >= a0
    __shared__ float Ka[64][68];
    __shared__ float Kb[64][68];
    const int t  = threadIdx.x;
    const int tb = t & 15;
    const int ta = t >> 4;
    float acc[4][4];
#pragma unroll
    for (int u = 0; u < 4; u++)
#pragma unroll
        for (int v = 0; v < 4; v++) acc[u][v] = 0.f;
    const int kmax = a0 + 64;        // K[k][a]=0 for k>a; a0 <= b0
    for (int k0 = 0; k0 < kmax; k0 += 64) {
#pragma unroll
        for (int q = 0; q < 4; q++) {
            const int f  = t + q * 256;
            const int kk = f >> 4;
            const int c4 = (f & 15) * 4;
            *reinterpret_cast<float4*>(&Ka[kk][c4]) =
                *reinterpret_cast<const float4*>(K + (k0 + kk) * NN + a0 + c4);
            *reinterpret_cast<float4*>(&Kb[kk][c4]) =
                *reinterpret_cast<const float4*>(K + (k0 + kk) * NN + b0 + c4);
        }
        __syncthreads();
#pragma unroll 8
        for (int kk = 0; kk < 64; kk++) {
            const float4 av = *reinterpret_cast<const float4*>(&Ka[kk][ta * 4]);
            const float4 bv = *reinterpret_cast<const float4*>(&Kb[kk][tb * 4]);
            const float a4[4] = {av.x, av.y, av.z, av.w};
            const float b4[4] = {bv.x, bv.y, bv.z, bv.w};
#pragma unroll
            for (int u = 0; u < 4; u++)
#pragma unroll
                for (int v = 0; v < 4; v++)
                    acc[u][v] = fmaf(a4[u], b4[v], acc[u][v]);
        }
        __syncthreads();
    }
#pragma unroll
    for (int u = 0; u < 4; u++) {
        float4 o;
        o.x = acc[u][0]; o.y = acc[u][1]; o.z = acc[u][2]; o.w = acc[u][3];
        *reinterpret_cast<float4*>(C + (a0 + ta * 4 + u) * NN + b0 + tb * 4) = o;
    }
    if (b0 > a0) {                   // mirror tile: C[b][a] = C[a][b], coalesced
#pragma unroll
        for (int v = 0; v < 4; v++) {
            float4 o;
            o.x = acc[0][v]; o.y = acc[1][v]; o.z = acc[2][v]; o.w = acc[3][v];
            *reinterpret_cast<float4*>(C + (b0 + tb * 4 + v) * NN + a0 + ta * 4) = o;
        }
    }
}

extern "C" void kernel_launch(void* const* d_in, const int* in_sizes, int n_in,
                              void* d_out, int out_size, void* d_ws, size_t ws_size,
                              hipStream_t stream)
{
    const float* x  = (const float*)d_in[0];
    const float* W1 = (const float*)d_in[1];
    const float* b1 = (const float*)d_in[2];
    const float* W2 = (const float*)d_in[3];
    const float* b2 = (const float*)d_in[4];
    const float* W3 = (const float*)d_in[5];
    const float* b3 = (const float*)d_in[6];
    float* Kmat = (float*)d_ws;                       // 2,359,296 B
    float* C    = (float*)d_out;

    const size_t kBytes = (size_t)NN * NN * sizeof(float);
    const size_t need   = kBytes + 262144;            // + W2 bf16 frag-major

    hipMemsetAsync(Kmat, 0, kBytes, stream);
    if (ws_size >= need) {
        ushort* WF = (ushort*)((char*)d_ws + kBytes);
        w2frag<<<64, 256, 0, stream>>>(W2, WF);
        mlp_pairs_reg<<<NPBLK2, 256, 0, stream>>>(x, W1, b1, WF, b2, W3, b3, Kmat);
    } else {
        mlp_fill<<<dim3(6, NN), 256, 0, stream>>>(x, W1, b1, W2, b2, W3, b3, Kmat);
    }
    ktk<<<dim3(NN / 64, NN / 64), 256, 0, stream>>>(Kmat, C);
}